// Round 4
// baseline (1308.736 us; speedup 1.0000x reference)
//
#include <hip/hip_runtime.h>

#define CIN 128
#define COUT 64
#define NXCD 8

// ---------------------------------------------------------------------------
// Kernel 1: h = x @ W_root + b ; m = x @ W_nbr   (unchanged — proven)
// ---------------------------------------------------------------------------
__global__ __launch_bounds__(256) void gemm_hm_kernel(
        const float* __restrict__ x,
        const float* __restrict__ Wr,
        const float* __restrict__ Wn,
        const float* __restrict__ b,
        float* __restrict__ h,
        float* __restrict__ m,
        int n_coarse) {
    __shared__ float xs[32][CIN];
    const int rowBase = blockIdx.x * 32;

    if (rowBase + 32 <= n_coarse) {
        const float4* x4 = (const float4*)(x + (long long)rowBase * CIN);
        float4* xs4 = (float4*)&xs[0][0];
        for (int i = threadIdx.x; i < 32 * (CIN / 4); i += 256) xs4[i] = x4[i];
    } else {
        for (int i = threadIdx.x; i < 32 * CIN; i += 256) {
            int r = i / CIN, k = i % CIN;
            int row = rowBase + r;
            xs[r][k] = (row < n_coarse) ? x[(long long)row * CIN + k] : 0.f;
        }
    }
    __syncthreads();

    const int wv = threadIdx.x >> 6;
    const int c  = threadIdx.x & 63;
    const int r0 = wv * 8;

    float ah[8], am[8];
    const float bias = b[c];
#pragma unroll
    for (int j = 0; j < 8; ++j) { ah[j] = bias; am[j] = 0.f; }

    for (int k = 0; k < CIN; k += 4) {
        const float wr0 = Wr[(k + 0) * COUT + c];
        const float wr1 = Wr[(k + 1) * COUT + c];
        const float wr2 = Wr[(k + 2) * COUT + c];
        const float wr3 = Wr[(k + 3) * COUT + c];
        const float wn0 = Wn[(k + 0) * COUT + c];
        const float wn1 = Wn[(k + 1) * COUT + c];
        const float wn2 = Wn[(k + 2) * COUT + c];
        const float wn3 = Wn[(k + 3) * COUT + c];
#pragma unroll
        for (int j = 0; j < 8; ++j) {
            const float4 xv = *(const float4*)&xs[r0 + j][k];
            ah[j] = fmaf(xv.x, wr0, ah[j]);
            ah[j] = fmaf(xv.y, wr1, ah[j]);
            ah[j] = fmaf(xv.z, wr2, ah[j]);
            ah[j] = fmaf(xv.w, wr3, ah[j]);
            am[j] = fmaf(xv.x, wn0, am[j]);
            am[j] = fmaf(xv.y, wn1, am[j]);
            am[j] = fmaf(xv.z, wn2, am[j]);
            am[j] = fmaf(xv.w, wn3, am[j]);
        }
    }

#pragma unroll
    for (int j = 0; j < 8; ++j) {
        const int row = rowBase + r0 + j;
        if (row < n_coarse) {
            h[row * COUT + c] = ah[j];
            m[row * COUT + c] = am[j];
        }
    }
}

// ---------------------------------------------------------------------------
// CSR build, pass 1 (XCD-partitioned): histogram of destination degrees.
// ---------------------------------------------------------------------------
__global__ __launch_bounds__(256) void hist_xcd_kernel(
        const int* __restrict__ dst, int* __restrict__ cnt, int n, int rpr) {
    const int range = blockIdx.x & (NXCD - 1);
    const int lo = range * rpr;
    const int hi = lo + rpr;
    const int tpr = (gridDim.x >> 3) * 256;           // threads per range
    const int ng = (n + 3) >> 2;                      // groups of 4 edges
    const int4* __restrict__ dst4 = (const int4*)dst;
    for (int g = (blockIdx.x >> 3) * 256 + threadIdx.x; g < ng; g += tpr) {
        const int e0 = g << 2;
        if (e0 + 3 < n) {
            const int4 d4 = dst4[g];
            if (d4.x >= lo && d4.x < hi) atomicAdd(&cnt[d4.x], 1);
            if (d4.y >= lo && d4.y < hi) atomicAdd(&cnt[d4.y], 1);
            if (d4.z >= lo && d4.z < hi) atomicAdd(&cnt[d4.z], 1);
            if (d4.w >= lo && d4.w < hi) atomicAdd(&cnt[d4.w], 1);
        } else {
            for (int k = 0; k < 4 && e0 + k < n; ++k) {
                const int d = dst[e0 + k];
                if (d >= lo && d < hi) atomicAdd(&cnt[d], 1);
            }
        }
    }
}

// ---------------------------------------------------------------------------
// CSR build, pass 2: per-block scan + one global cursor atomic.
// ---------------------------------------------------------------------------
__global__ __launch_bounds__(256) void assign_base_kernel(
        const int* __restrict__ cnt, int* __restrict__ base,
        int* __restrict__ fill, int* __restrict__ cursor, int n) {
    __shared__ int s[256];
    __shared__ int blockBase;
    const int tid = threadIdx.x;
    const int i = blockIdx.x * 256 + tid;
    const int v = (i < n) ? cnt[i] : 0;
    s[tid] = v;
    __syncthreads();
#pragma unroll
    for (int off = 1; off < 256; off <<= 1) {
        int t = (tid >= off) ? s[tid - off] : 0;
        __syncthreads();
        if (tid >= off) s[tid] += t;
        __syncthreads();
    }
    if (tid == 255) blockBase = atomicAdd(cursor, s[255]);
    __syncthreads();
    if (i < n) {
        const int bse = blockBase + s[tid] - v;   // exclusive scan
        base[i] = bse;
        fill[i] = bse;
    }
}

// ---------------------------------------------------------------------------
// CSR build, pass 3 (XCD-partitioned scatter).
// ---------------------------------------------------------------------------
__global__ __launch_bounds__(256) void scatter_xcd_kernel(
        const int* __restrict__ src, const int* __restrict__ dst,
        const float* __restrict__ w, int* __restrict__ fill,
        int2* __restrict__ edges, int n, int rpr) {
    const int range = blockIdx.x & (NXCD - 1);
    const int lo = range * rpr;
    const int hi = lo + rpr;
    const int tpr = (gridDim.x >> 3) * 256;
    const int ng = (n + 3) >> 2;
    const int4* __restrict__ dst4 = (const int4*)dst;
    for (int g = (blockIdx.x >> 3) * 256 + threadIdx.x; g < ng; g += tpr) {
        const int e0 = g << 2;
        if (e0 + 3 < n) {
            const int4 d4 = dst4[g];
            const int dd[4] = {d4.x, d4.y, d4.z, d4.w};
#pragma unroll
            for (int k = 0; k < 4; ++k) {
                const int d = dd[k];
                if (d >= lo && d < hi) {
                    const int pos = atomicAdd(&fill[d], 1);
                    edges[pos] = make_int2(src[e0 + k] * COUT,
                                           __float_as_int(w[e0 + k]));
                }
            }
        } else {
            for (int k = 0; k < 4 && e0 + k < n; ++k) {
                const int d = dst[e0 + k];
                if (d >= lo && d < hi) {
                    const int pos = atomicAdd(&fill[d], 1);
                    edges[pos] = make_int2(src[e0 + k] * COUT,
                                           __float_as_int(w[e0 + k]));
                }
            }
        }
    }
}

// ---------------------------------------------------------------------------
// Batched + pipelined CSR row reduction.
// All loads of a chunk issue before any is consumed; the next chunk's
// records issue concurrently with this chunk's value gathers. The sub-8
// tail issues all 8 record loads with indices CLAMPED to the row's own
// range (duplicate loads hit the same cache line, stay independent, and
// require no out-of-bounds layout assumptions); weights for j+k >= n are
// masked to 0.
// ---------------------------------------------------------------------------
__device__ __forceinline__ float csr_row_dot(
        const float* __restrict__ buf,
        const int2* __restrict__ ep,
        int n, int c) {
    float acc = 0.f;
    int j = 0;
    if (n >= 8) {
        int2 e[8];
#pragma unroll
        for (int k = 0; k < 8; ++k) e[k] = ep[k];
        j = 8;
        while (j + 8 <= n) {           // e holds records of chunk [j-8, j)
            float v[8];
#pragma unroll
            for (int k = 0; k < 8; ++k) v[k] = buf[e[k].x + c];
            int2 en[8];
#pragma unroll
            for (int k = 0; k < 8; ++k) en[k] = ep[j + k];
#pragma unroll
            for (int k = 0; k < 8; ++k) acc = fmaf(v[k], __int_as_float(e[k].y), acc);
#pragma unroll
            for (int k = 0; k < 8; ++k) e[k] = en[k];
            j += 8;
        }
        {   // drain last full chunk
            float v[8];
#pragma unroll
            for (int k = 0; k < 8; ++k) v[k] = buf[e[k].x + c];
#pragma unroll
            for (int k = 0; k < 8; ++k) acc = fmaf(v[k], __int_as_float(e[k].y), acc);
        }
    }
    if (j < n) {                        // tail: 1..7 records, clamped loads
        int2 et[8];
#pragma unroll
        for (int k = 0; k < 8; ++k) {
            int idx = j + k;
            idx = (idx < n) ? idx : (n - 1);   // n >= 1 here
            et[k] = ep[idx];
        }
        float v[8];
#pragma unroll
        for (int k = 0; k < 8; ++k) v[k] = buf[et[k].x + c];
#pragma unroll
        for (int k = 0; k < 8; ++k) {
            const float wk = (j + k < n) ? __int_as_float(et[k].y) : 0.f;
            acc = fmaf(v[k], wk, acc);
        }
    }
    return acc;
}

__global__ __launch_bounds__(256) void csr_gather_add_kernel(
        const float* __restrict__ m,
        const int* __restrict__ base, const int* __restrict__ cnt,
        const int2* __restrict__ edges,
        float* __restrict__ h, int n_rows) {
    const int row = blockIdx.x * 4 + (threadIdx.x >> 6);
    const int c = threadIdx.x & 63;
    if (row >= n_rows) return;
    const float acc = csr_row_dot(m, edges + base[row], cnt[row], c);
    h[row * COUT + c] += acc;
}

__global__ __launch_bounds__(256) void csr_gather_write_kernel(
        const float* __restrict__ h,
        const int* __restrict__ base, const int* __restrict__ cnt,
        const int2* __restrict__ edges,
        float* __restrict__ y, int n_rows) {
    const int row = blockIdx.x * 4 + (threadIdx.x >> 6);
    const int c = threadIdx.x & 63;
    if (row >= n_rows) return;
    const float acc = csr_row_dot(h, edges + base[row], cnt[row], c);
    y[row * COUT + c] = acc;   // full coverage -> no memset needed
}

extern "C" void kernel_launch(void* const* d_in, const int* in_sizes, int n_in,
                              void* d_out, int out_size, void* d_ws, size_t ws_size,
                              hipStream_t stream) {
    const float* x      = (const float*)d_in[0];
    const float* W_root = (const float*)d_in[1];
    const float* W_nbr  = (const float*)d_in[2];
    const float* b      = (const float*)d_in[3];
    const int*   eidx   = (const int*)d_in[4];   // [2, E]: row0=src, row1=dst
    const float* eattr  = (const float*)d_in[5];
    const int*   psrc   = (const int*)d_in[6];
    const int*   pdst   = (const int*)d_in[7];
    const float* pattr  = (const float*)d_in[8];

    const int n_coarse = in_sizes[0] / CIN;      // 200000
    const int n_edges  = in_sizes[4] / 2;        // 3200000
    const int n_pool   = in_sizes[6];            // 2400000
    const int n_fine   = out_size / COUT;        // 800000

    const int* esrc = eidx;
    const int* edst = eidx + n_edges;

    // ws layout (102.4 MB, unchanged footprint):
    float* h = (float*)d_ws;                       // [Nc, 64]  51.2 MB
    float* m = h + (size_t)n_coarse * COUT;        // [Nc, 64]  51.2 MB

    // Phase-1 CSR scratch lives in d_out (dead until the final kernel):
    char* outb = (char*)d_out;
    int2* edges1  = (int2*)outb;
    char* p1      = outb + (size_t)n_edges * sizeof(int2);
    int*  cnt1    = (int*)p1;
    int*  cursor1 = (int*)(p1 + (size_t)n_coarse * 4);
    int*  base1   = (int*)(p1 + (size_t)n_coarse * 4 + 16);
    int*  fill1   = (int*)(p1 + (size_t)n_coarse * 4 + 16 + (size_t)n_coarse * 4);

    // Phase-2 CSR scratch overlays m (dead after edge gather):
    char* mb      = (char*)m;
    int2* edges2  = (int2*)mb;
    char* p2      = mb + (size_t)n_pool * sizeof(int2);
    int*  cnt2    = (int*)p2;
    int*  cursor2 = (int*)(p2 + (size_t)n_fine * 4);
    int*  base2   = (int*)(p2 + (size_t)n_fine * 4 + 16);
    int*  fill2   = (int*)(p2 + (size_t)n_fine * 4 + 16 + (size_t)n_fine * 4);

    const int rpr1 = (n_coarse + NXCD - 1) / NXCD;   // rows per XCD range
    const int rpr2 = (n_fine + NXCD - 1) / NXCD;

    // 1) dense transforms: h = x@Wr + b, m = x@Wn
    gemm_hm_kernel<<<(n_coarse + 31) / 32, 256, 0, stream>>>(x, W_root, W_nbr, b, h, m, n_coarse);

    // 2) phase-1 CSR build (scratch in d_out)
    hipMemsetAsync(cnt1, 0, (size_t)n_coarse * 4 + 16, stream);   // cnt1 + cursor1
    hist_xcd_kernel<<<2048, 256, 0, stream>>>(edst, cnt1, n_edges, rpr1);
    assign_base_kernel<<<(n_coarse + 255) / 256, 256, 0, stream>>>(cnt1, base1, fill1, cursor1, n_coarse);
    scatter_xcd_kernel<<<2048, 256, 0, stream>>>(esrc, edst, eattr, fill1, edges1, n_edges, rpr1);

    // 3) edge aggregation: h += sum over in-edges of m[src]*w
    csr_gather_add_kernel<<<(n_coarse + 3) / 4, 256, 0, stream>>>(
        m, base1, cnt1, edges1, h, n_coarse);

    // 4) phase-2 CSR build (m buffer is now dead; reuse it)
    hipMemsetAsync(cnt2, 0, (size_t)n_fine * 4 + 16, stream);     // cnt2 + cursor2
    hist_xcd_kernel<<<2048, 256, 0, stream>>>(pdst, cnt2, n_pool, rpr2);
    assign_base_kernel<<<(n_fine + 255) / 256, 256, 0, stream>>>(cnt2, base2, fill2, cursor2, n_fine);
    scatter_xcd_kernel<<<2048, 256, 0, stream>>>(psrc, pdst, pattr, fill2, edges2, n_pool, rpr2);

    // 5) unpool gather: every output row written exactly once
    csr_gather_write_kernel<<<(n_fine + 3) / 4, 256, 0, stream>>>(
        h, base2, cnt2, edges2, (float*)d_out, n_fine);
}

// Round 5
// 1205.374 us; speedup vs baseline: 1.0858x; 1.0858x over previous
//
#include <hip/hip_runtime.h>

#define CIN 128
#define COUT 64
#define NXCD 8

// ---------------------------------------------------------------------------
// Kernel 1: h = x @ W_root + b ; m = x @ W_nbr   (unchanged — proven)
// ---------------------------------------------------------------------------
__global__ __launch_bounds__(256) void gemm_hm_kernel(
        const float* __restrict__ x,
        const float* __restrict__ Wr,
        const float* __restrict__ Wn,
        const float* __restrict__ b,
        float* __restrict__ h,
        float* __restrict__ m,
        int n_coarse) {
    __shared__ float xs[32][CIN];
    const int rowBase = blockIdx.x * 32;

    if (rowBase + 32 <= n_coarse) {
        const float4* x4 = (const float4*)(x + (long long)rowBase * CIN);
        float4* xs4 = (float4*)&xs[0][0];
        for (int i = threadIdx.x; i < 32 * (CIN / 4); i += 256) xs4[i] = x4[i];
    } else {
        for (int i = threadIdx.x; i < 32 * CIN; i += 256) {
            int r = i / CIN, k = i % CIN;
            int row = rowBase + r;
            xs[r][k] = (row < n_coarse) ? x[(long long)row * CIN + k] : 0.f;
        }
    }
    __syncthreads();

    const int wv = threadIdx.x >> 6;
    const int c  = threadIdx.x & 63;
    const int r0 = wv * 8;

    float ah[8], am[8];
    const float bias = b[c];
#pragma unroll
    for (int j = 0; j < 8; ++j) { ah[j] = bias; am[j] = 0.f; }

    for (int k = 0; k < CIN; k += 4) {
        const float wr0 = Wr[(k + 0) * COUT + c];
        const float wr1 = Wr[(k + 1) * COUT + c];
        const float wr2 = Wr[(k + 2) * COUT + c];
        const float wr3 = Wr[(k + 3) * COUT + c];
        const float wn0 = Wn[(k + 0) * COUT + c];
        const float wn1 = Wn[(k + 1) * COUT + c];
        const float wn2 = Wn[(k + 2) * COUT + c];
        const float wn3 = Wn[(k + 3) * COUT + c];
#pragma unroll
        for (int j = 0; j < 8; ++j) {
            const float4 xv = *(const float4*)&xs[r0 + j][k];
            ah[j] = fmaf(xv.x, wr0, ah[j]);
            ah[j] = fmaf(xv.y, wr1, ah[j]);
            ah[j] = fmaf(xv.z, wr2, ah[j]);
            ah[j] = fmaf(xv.w, wr3, ah[j]);
            am[j] = fmaf(xv.x, wn0, am[j]);
            am[j] = fmaf(xv.y, wn1, am[j]);
            am[j] = fmaf(xv.z, wn2, am[j]);
            am[j] = fmaf(xv.w, wn3, am[j]);
        }
    }

#pragma unroll
    for (int j = 0; j < 8; ++j) {
        const int row = rowBase + r0 + j;
        if (row < n_coarse) {
            h[row * COUT + c] = ah[j];
            m[row * COUT + c] = am[j];
        }
    }
}

// ---------------------------------------------------------------------------
// CSR build, pass 1 (XCD-partitioned): histogram of destination degrees.
// ---------------------------------------------------------------------------
__global__ __launch_bounds__(256) void hist_xcd_kernel(
        const int* __restrict__ dst, int* __restrict__ cnt, int n, int rpr) {
    const int range = blockIdx.x & (NXCD - 1);
    const int lo = range * rpr;
    const int hi = lo + rpr;
    const int tpr = (gridDim.x >> 3) * 256;           // threads per range
    const int ng = (n + 3) >> 2;                      // groups of 4 edges
    const int4* __restrict__ dst4 = (const int4*)dst;
    for (int g = (blockIdx.x >> 3) * 256 + threadIdx.x; g < ng; g += tpr) {
        const int e0 = g << 2;
        if (e0 + 3 < n) {
            const int4 d4 = dst4[g];
            if (d4.x >= lo && d4.x < hi) atomicAdd(&cnt[d4.x], 1);
            if (d4.y >= lo && d4.y < hi) atomicAdd(&cnt[d4.y], 1);
            if (d4.z >= lo && d4.z < hi) atomicAdd(&cnt[d4.z], 1);
            if (d4.w >= lo && d4.w < hi) atomicAdd(&cnt[d4.w], 1);
        } else {
            for (int k = 0; k < 4 && e0 + k < n; ++k) {
                const int d = dst[e0 + k];
                if (d >= lo && d < hi) atomicAdd(&cnt[d], 1);
            }
        }
    }
}

// ---------------------------------------------------------------------------
// CSR build, pass 2: per-block scan + one global cursor atomic.
// ---------------------------------------------------------------------------
__global__ __launch_bounds__(256) void assign_base_kernel(
        const int* __restrict__ cnt, int* __restrict__ base,
        int* __restrict__ fill, int* __restrict__ cursor, int n) {
    __shared__ int s[256];
    __shared__ int blockBase;
    const int tid = threadIdx.x;
    const int i = blockIdx.x * 256 + tid;
    const int v = (i < n) ? cnt[i] : 0;
    s[tid] = v;
    __syncthreads();
#pragma unroll
    for (int off = 1; off < 256; off <<= 1) {
        int t = (tid >= off) ? s[tid - off] : 0;
        __syncthreads();
        if (tid >= off) s[tid] += t;
        __syncthreads();
    }
    if (tid == 255) blockBase = atomicAdd(cursor, s[255]);
    __syncthreads();
    if (i < n) {
        const int bse = blockBase + s[tid] - v;   // exclusive scan
        base[i] = bse;
        fill[i] = bse;
    }
}

// ---------------------------------------------------------------------------
// CSR build, pass 3 (XCD-partitioned scatter).
// ---------------------------------------------------------------------------
__global__ __launch_bounds__(256) void scatter_xcd_kernel(
        const int* __restrict__ src, const int* __restrict__ dst,
        const float* __restrict__ w, int* __restrict__ fill,
        int2* __restrict__ edges, int n, int rpr) {
    const int range = blockIdx.x & (NXCD - 1);
    const int lo = range * rpr;
    const int hi = lo + rpr;
    const int tpr = (gridDim.x >> 3) * 256;
    const int ng = (n + 3) >> 2;
    const int4* __restrict__ dst4 = (const int4*)dst;
    for (int g = (blockIdx.x >> 3) * 256 + threadIdx.x; g < ng; g += tpr) {
        const int e0 = g << 2;
        if (e0 + 3 < n) {
            const int4 d4 = dst4[g];
            const int dd[4] = {d4.x, d4.y, d4.z, d4.w};
#pragma unroll
            for (int k = 0; k < 4; ++k) {
                const int d = dd[k];
                if (d >= lo && d < hi) {
                    const int pos = atomicAdd(&fill[d], 1);
                    edges[pos] = make_int2(src[e0 + k] * COUT,
                                           __float_as_int(w[e0 + k]));
                }
            }
        } else {
            for (int k = 0; k < 4 && e0 + k < n; ++k) {
                const int d = dst[e0 + k];
                if (d >= lo && d < hi) {
                    const int pos = atomicAdd(&fill[d], 1);
                    edges[pos] = make_int2(src[e0 + k] * COUT,
                                           __float_as_int(w[e0 + k]));
                }
            }
        }
    }
}

// ---------------------------------------------------------------------------
// CSR gathers: 4 rows per wave, 16 lanes per row, float4 per lane.
// Each 16-lane group walks its own edge list with a 1-deep record prefetch
// (next record load issues while the current row gather is in flight).
// A wave holds ~4 record loads + 4 row gathers outstanding — all useful,
// no duplicate traffic. Degree divergence within the wave is exec-masked
// (costs issue slots only).
// ---------------------------------------------------------------------------
__device__ __forceinline__ float4 csr_row_dot4(
        const float* __restrict__ buf,
        const int2* __restrict__ ep,
        int n, int t) {
    float4 acc = make_float4(0.f, 0.f, 0.f, 0.f);
    if (n > 0) {
        int2 rec = ep[0];
        for (int j = 1; j < n; ++j) {
            const int2 nrec = ep[j];                       // prefetch next
            const float4 v = *(const float4*)(buf + rec.x + (t << 2));
            const float w = __int_as_float(rec.y);
            acc.x = fmaf(v.x, w, acc.x);
            acc.y = fmaf(v.y, w, acc.y);
            acc.z = fmaf(v.z, w, acc.z);
            acc.w = fmaf(v.w, w, acc.w);
            rec = nrec;
        }
        const float4 v = *(const float4*)(buf + rec.x + (t << 2));
        const float w = __int_as_float(rec.y);
        acc.x = fmaf(v.x, w, acc.x);
        acc.y = fmaf(v.y, w, acc.y);
        acc.z = fmaf(v.z, w, acc.z);
        acc.w = fmaf(v.w, w, acc.w);
    }
    return acc;
}

__global__ __launch_bounds__(256) void csr_gather4_add_kernel(
        const float* __restrict__ m,
        const int* __restrict__ base, const int* __restrict__ cnt,
        const int2* __restrict__ edges,
        float* __restrict__ h, int n_rows) {
    const int wave = threadIdx.x >> 6;
    const int lane = threadIdx.x & 63;
    const int g    = lane >> 4;            // row sub-group 0..3
    const int t    = lane & 15;            // float4 slot within row
    const int row  = blockIdx.x * 16 + wave * 4 + g;
    if (row >= n_rows) return;
    const float4 acc = csr_row_dot4(m, edges + base[row], cnt[row], t);
    float4* hp = (float4*)(h + (size_t)row * COUT) + t;
    float4 hv = *hp;
    hv.x += acc.x; hv.y += acc.y; hv.z += acc.z; hv.w += acc.w;
    *hp = hv;
}

__global__ __launch_bounds__(256) void csr_gather4_write_kernel(
        const float* __restrict__ h,
        const int* __restrict__ base, const int* __restrict__ cnt,
        const int2* __restrict__ edges,
        float* __restrict__ y, int n_rows) {
    const int wave = threadIdx.x >> 6;
    const int lane = threadIdx.x & 63;
    const int g    = lane >> 4;
    const int t    = lane & 15;
    const int row  = blockIdx.x * 16 + wave * 4 + g;
    if (row >= n_rows) return;
    const float4 acc = csr_row_dot4(h, edges + base[row], cnt[row], t);
    *((float4*)(y + (size_t)row * COUT) + t) = acc;   // full coverage
}

extern "C" void kernel_launch(void* const* d_in, const int* in_sizes, int n_in,
                              void* d_out, int out_size, void* d_ws, size_t ws_size,
                              hipStream_t stream) {
    const float* x      = (const float*)d_in[0];
    const float* W_root = (const float*)d_in[1];
    const float* W_nbr  = (const float*)d_in[2];
    const float* b      = (const float*)d_in[3];
    const int*   eidx   = (const int*)d_in[4];   // [2, E]: row0=src, row1=dst
    const float* eattr  = (const float*)d_in[5];
    const int*   psrc   = (const int*)d_in[6];
    const int*   pdst   = (const int*)d_in[7];
    const float* pattr  = (const float*)d_in[8];

    const int n_coarse = in_sizes[0] / CIN;      // 200000
    const int n_edges  = in_sizes[4] / 2;        // 3200000
    const int n_pool   = in_sizes[6];            // 2400000
    const int n_fine   = out_size / COUT;        // 800000

    const int* esrc = eidx;
    const int* edst = eidx + n_edges;

    // ws layout (102.4 MB, unchanged footprint):
    float* h = (float*)d_ws;                       // [Nc, 64]  51.2 MB
    float* m = h + (size_t)n_coarse * COUT;        // [Nc, 64]  51.2 MB

    // Phase-1 CSR scratch lives in d_out (dead until the final kernel):
    char* outb = (char*)d_out;
    int2* edges1  = (int2*)outb;
    char* p1      = outb + (size_t)n_edges * sizeof(int2);
    int*  cnt1    = (int*)p1;
    int*  cursor1 = (int*)(p1 + (size_t)n_coarse * 4);
    int*  base1   = (int*)(p1 + (size_t)n_coarse * 4 + 16);
    int*  fill1   = (int*)(p1 + (size_t)n_coarse * 4 + 16 + (size_t)n_coarse * 4);

    // Phase-2 CSR scratch overlays m (dead after edge gather):
    char* mb      = (char*)m;
    int2* edges2  = (int2*)mb;
    char* p2      = mb + (size_t)n_pool * sizeof(int2);
    int*  cnt2    = (int*)p2;
    int*  cursor2 = (int*)(p2 + (size_t)n_fine * 4);
    int*  base2   = (int*)(p2 + (size_t)n_fine * 4 + 16);
    int*  fill2   = (int*)(p2 + (size_t)n_fine * 4 + 16 + (size_t)n_fine * 4);

    const int rpr1 = (n_coarse + NXCD - 1) / NXCD;   // rows per XCD range
    const int rpr2 = (n_fine + NXCD - 1) / NXCD;

    // 1) dense transforms: h = x@Wr + b, m = x@Wn
    gemm_hm_kernel<<<(n_coarse + 31) / 32, 256, 0, stream>>>(x, W_root, W_nbr, b, h, m, n_coarse);

    // 2) phase-1 CSR build (scratch in d_out)
    hipMemsetAsync(cnt1, 0, (size_t)n_coarse * 4 + 16, stream);   // cnt1 + cursor1
    hist_xcd_kernel<<<2048, 256, 0, stream>>>(edst, cnt1, n_edges, rpr1);
    assign_base_kernel<<<(n_coarse + 255) / 256, 256, 0, stream>>>(cnt1, base1, fill1, cursor1, n_coarse);
    scatter_xcd_kernel<<<2048, 256, 0, stream>>>(esrc, edst, eattr, fill1, edges1, n_edges, rpr1);

    // 3) edge aggregation: h += sum over in-edges of m[src]*w
    csr_gather4_add_kernel<<<(n_coarse + 15) / 16, 256, 0, stream>>>(
        m, base1, cnt1, edges1, h, n_coarse);

    // 4) phase-2 CSR build (m buffer is now dead; reuse it)
    hipMemsetAsync(cnt2, 0, (size_t)n_fine * 4 + 16, stream);     // cnt2 + cursor2
    hist_xcd_kernel<<<2048, 256, 0, stream>>>(pdst, cnt2, n_pool, rpr2);
    assign_base_kernel<<<(n_fine + 255) / 256, 256, 0, stream>>>(cnt2, base2, fill2, cursor2, n_fine);
    scatter_xcd_kernel<<<2048, 256, 0, stream>>>(psrc, pdst, pattr, fill2, edges2, n_pool, rpr2);

    // 5) unpool gather: every output row written exactly once
    csr_gather4_write_kernel<<<(n_fine + 15) / 16, 256, 0, stream>>>(
        h, base2, cnt2, edges2, (float*)d_out, n_fine);
}